// Round 3
// baseline (7621.300 us; speedup 1.0000x reference)
//
#include <hip/hip_runtime.h>
#include <hip/hip_bf16.h>

#define EPSF 1e-20f

// storage-type load/store helpers (compute is always fp32)
__device__ __forceinline__ float ldv(const float* p) { return *p; }
__device__ __forceinline__ float ldv(const __hip_bfloat16* p) { return __bfloat162float(*p); }
__device__ __forceinline__ void stv(float* p, float v) { *p = v; }
__device__ __forceinline__ void stv(__hip_bfloat16* p, float v) { *p = __float2bfloat16(v); }

// ---------------------------------------------------------------------------
// Weight prep: s[co] = sum over (ci,kh,kw); transpose to [ci][tap][co] so the
// conv inner loop reads weights at thread-uniform addresses (s_load).
// ---------------------------------------------------------------------------
__global__ void wsum_k(const float* __restrict__ w, float* __restrict__ s, int n) {
    int co = threadIdx.x;  // 32 threads
    float acc = 0.f;
    for (int i = 0; i < n; ++i) acc += w[co * n + i];
    s[co] = acc;
}

// wt[((ci^cxor)*KK + t)*32 + co] = w[co][ci][t]
__global__ void wtr_k(const float* __restrict__ w, float* __restrict__ wt,
                      int CIN, int KK, int cxor) {
    int idx = blockIdx.x * 256 + threadIdx.x;
    int total = 32 * CIN * KK;
    if (idx >= total) return;
    int co = idx / (CIN * KK);
    int r = idx % (CIN * KK);
    int ci = r / KK;
    int t = r % KK;
    wt[(((ci ^ cxor) * KK) + t) * 32 + co] = w[idx];
}

// ---------------------------------------------------------------------------
// Normalized conv. Source1: CIN1 channels at full res, per-(local)batch
// stride bs1. Source2 (cat): CIN2 channels at half res, nearest-upsampled
// in-kernel, plane layout [lb*CIN2+ci].
// RAWIN: source1 holds raw (x, c); p = x*c computed on the fly [first conv].
// FUSE7: apply the final 1x1 nconv (w7,b7) in the epilogue, write x to xout.
// Each thread: 1 output pixel, all 32 output channels in registers.
// blockIdx.z = local batch lb in [0, NB).
// ---------------------------------------------------------------------------
template <typename IT, typename OT, int CIN1, int CIN2, int KS, bool RAWIN, bool FUSE7>
__global__ __launch_bounds__(256)
void nconv_k(const IT* __restrict__ p1, const IT* __restrict__ c1, long bs1,
             const IT* __restrict__ p2, const IT* __restrict__ c2,
             const float* __restrict__ wt, const float* __restrict__ bias,
             const float* __restrict__ sden,
             OT* __restrict__ pout, OT* __restrict__ cout,
             const float* __restrict__ w7, const float* __restrict__ b7,
             float* __restrict__ xout,
             int H, int W) {
    constexpr int R = KS / 2;
    constexpr int KK = KS * KS;
    const int tx = threadIdx.x & 31, ty = threadIdx.x >> 5;
    const int x = blockIdx.x * 32 + tx;
    const int y = blockIdx.y * 8 + ty;
    const int lb = blockIdx.z;
    const long HWl = (long)H * W;

    int off[KK];
    bool ok[KK];
    int off2[KK];
#pragma unroll
    for (int kh = 0; kh < KS; ++kh) {
#pragma unroll
        for (int kw = 0; kw < KS; ++kw) {
            int t = kh * KS + kw;
            int r = y + kh - R, cc = x + kw - R;
            bool v = (r >= 0) & (r < H) & (cc >= 0) & (cc < W);
            ok[t] = v;
            off[t] = v ? (r * W + cc) : 0;
            if (CIN2 > 0) off2[t] = v ? ((r >> 1) * (W >> 1) + (cc >> 1)) : 0;
        }
    }

    float ac[32], ap[32];
#pragma unroll
    for (int i = 0; i < 32; ++i) { ac[i] = 0.f; ap[i] = 0.f; }

    // ---- source 1 (same resolution) ----
    for (int ci = 0; ci < CIN1; ++ci) {
        const IT* pb = p1 + (long)lb * bs1 + (long)ci * HWl;
        const IT* cb = c1 + (long)lb * bs1 + (long)ci * HWl;
        const float* wr = wt + (long)ci * KK * 32;
#pragma unroll
        for (int t = 0; t < KK; ++t) {
            float lc = ldv(cb + off[t]);
            float lp = ldv(pb + off[t]);
            float cv = ok[t] ? lc : 0.f;
            float pv = ok[t] ? lp : 0.f;
            if (RAWIN) pv *= cv;  // p = x*c computed on the fly
#pragma unroll
            for (int co = 0; co < 32; ++co) {
                float wv = wr[t * 32 + co];  // uniform addr -> s_load
                ac[co] = fmaf(wv, cv, ac[co]);
                ap[co] = fmaf(wv, pv, ap[co]);
            }
        }
    }

    // ---- source 2 (half resolution, nearest-upsampled) ----
    if (CIN2 > 0) {
        const int H2 = H >> 1, W2 = W >> 1;
        const long HW2 = (long)H2 * W2;
        for (int ci = 0; ci < CIN2; ++ci) {
            const IT* pb = p2 + ((long)lb * CIN2 + ci) * HW2;
            const IT* cb = c2 + ((long)lb * CIN2 + ci) * HW2;
            const float* wr = wt + (long)(CIN1 + ci) * KK * 32;
#pragma unroll
            for (int t = 0; t < KK; ++t) {
                float lc = ldv(cb + off2[t]);
                float lp = ldv(pb + off2[t]);
                float cv = ok[t] ? lc : 0.f;
                float pv = ok[t] ? lp : 0.f;
#pragma unroll
                for (int co = 0; co < 32; ++co) {
                    float wv = wr[t * 32 + co];
                    ac[co] = fmaf(wv, cv, ac[co]);
                    ap[co] = fmaf(wv, pv, ap[co]);
                }
            }
        }
    }

    // ---- epilogue ----
    if (!FUSE7) {
        const long ob = ((long)lb * 32) * HWl + (long)y * W + x;
#pragma unroll
        for (int co = 0; co < 32; ++co) {
            float d = ac[co];
            float ox = ap[co] / (d + EPSF) + bias[co];
            float oc = d / sden[co];
            stv(pout + ob + (long)co * HWl, ox * oc);
            stv(cout + ob + (long)co * HWl, oc);
        }
    } else {
        float num = 0.f, den = 0.f;
#pragma unroll
        for (int co = 0; co < 32; ++co) {
            float d = ac[co];
            float ox = ap[co] / (d + EPSF) + bias[co];
            float oc = d / sden[co];
            num = fmaf(w7[co], ox * oc, num);
            den = fmaf(w7[co], oc, den);
        }
        xout[(long)lb * HWl + (long)y * W + x] = num / (den + EPSF) + b7[0];
    }
}

// ---------------------------------------------------------------------------
// 2x2 stride-2 pool: argmax of c (first-max, row-major window order),
// gather p; both scaled by 1/4 (c_out = c_max/4, p_out = p[argmax]/4).
// total = (#planes)*Ho*Wo where #planes = NB*32; plane layout matches conv.
// ---------------------------------------------------------------------------
template <typename T>
__global__ void pool_k(const T* __restrict__ pin, const T* __restrict__ cin,
                       T* __restrict__ pout, T* __restrict__ cout,
                       int Ho, int Wo, int total) {
    int idx = blockIdx.x * 256 + threadIdx.x;
    if (idx >= total) return;
    int w = idx % Wo;
    int t = idx / Wo;
    int h = t % Ho;
    int pl = t / Ho;
    const long ibase = ((long)pl * 4 * Ho * Wo) + (long)(2 * h) * (2 * Wo) + 2 * w;
    float c00 = ldv(cin + ibase),          c01 = ldv(cin + ibase + 1);
    float c10 = ldv(cin + ibase + 2 * Wo), c11 = ldv(cin + ibase + 2 * Wo + 1);
    float p00 = ldv(pin + ibase),          p01 = ldv(pin + ibase + 1);
    float p10 = ldv(pin + ibase + 2 * Wo), p11 = ldv(pin + ibase + 2 * Wo + 1);
    float bv = c00, bp = p00;
    if (c01 > bv) { bv = c01; bp = p01; }
    if (c10 > bv) { bv = c10; bp = p10; }
    if (c11 > bv) { bv = c11; bp = p11; }
    stv(cout + idx, bv * 0.25f);
    stv(pout + idx, bp * 0.25f);
}

// ---------------------------------------------------------------------------
// Whole network for storage type T over NB batches (x/dout pre-offset by the
// caller for multi-pass). Buffer arena `base` layout:
//   [ A (p,c) | B (p,c) ]  each plane group = NB*32*HW1 elements.
// All lower-res buffers alias the B region (lifetimes disjoint from B).
// Weight buffers are prepped once by the caller.
// ---------------------------------------------------------------------------
template <typename T>
static void run_net(const float* x,
                    const float* b1, const float* b2, const float* b3,
                    const float* b4, const float* b5, const float* b6,
                    const float* w7, const float* b7,
                    const float* wt1, const float* wt2, const float* wt3,
                    const float* wt4, const float* wt5, const float* wt6,
                    const float* s1, const float* s2, const float* s3,
                    const float* s4, const float* s5, const float* s6,
                    float* dout, T* base, int NB, hipStream_t stream) {
    const size_t HW1 = 512 * 512, HW2 = 256 * 256, HW3 = 128 * 128, HW4 = 64 * 64;
    const size_t PL1 = (size_t)NB * 32 * HW1;  // elements per full-res plane group
    const size_t PL2 = (size_t)NB * 32 * HW2;
    const size_t PL3 = (size_t)NB * 32 * HW3;
    const size_t PL4 = (size_t)NB * 32 * HW4;

    T* Ap = base;      T* Ac = Ap + PL1;
    T* Bp = Ac + PL1;  T* Bc = Bp + PL1;
    // lower-res alias region inside B: 4*PL2+4*PL3+4*PL4 = 0.656*PL1 <= 2*PL1
    T* Pp = Bp;        T* Pc = Pp + PL2;
    T* Qp = Pc + PL2;  T* Qc = Qp + PL2;
    T* Sp = Qc + PL2;  T* Sc = Sp + PL3;
    T* Tp = Sc + PL3;  T* Tc = Tp + PL3;
    T* Up = Tc + PL3;  T* Uc = Up + PL4;
    T* Vp = Uc + PL4;  T* Vc = Vp + PL4;

    dim3 blk(256);
    dim3 g1(512 / 32, 512 / 8, NB);
    dim3 g2(256 / 32, 256 / 8, NB);
    dim3 g3(128 / 32, 128 / 8, NB);
    dim3 g4(64 / 32, 64 / 8, NB);

    // encoder (input x: [b][plane][512][512], plane0 = data, plane1 = conf)
    nconv_k<float, T, 1, 0, 5, true, false><<<g1, blk, 0, stream>>>(
        x, x + HW1, (long)(2 * HW1), (const float*)nullptr, (const float*)nullptr,
        wt1, b1, s1, Ap, Ac, nullptr, nullptr, nullptr, 512, 512);
    nconv_k<T, T, 32, 0, 5, false, false><<<g1, blk, 0, stream>>>(
        Ap, Ac, (long)(32 * HW1), (const T*)nullptr, (const T*)nullptr,
        wt2, b2, s2, Bp, Bc, nullptr, nullptr, nullptr, 512, 512);
    nconv_k<T, T, 32, 0, 5, false, false><<<g1, blk, 0, stream>>>(
        Bp, Bc, (long)(32 * HW1), (const T*)nullptr, (const T*)nullptr,
        wt3, b3, s3, Ap, Ac, nullptr, nullptr, nullptr, 512, 512);  // x1 in A

    pool_k<T><<<(int)(PL2 / 256), blk, 0, stream>>>(Ap, Ac, Pp, Pc, 256, 256, (int)PL2);
    nconv_k<T, T, 32, 0, 5, false, false><<<g2, blk, 0, stream>>>(
        Pp, Pc, (long)(32 * HW2), (const T*)nullptr, (const T*)nullptr,
        wt2, b2, s2, Qp, Qc, nullptr, nullptr, nullptr, 256, 256);
    nconv_k<T, T, 32, 0, 5, false, false><<<g2, blk, 0, stream>>>(
        Qp, Qc, (long)(32 * HW2), (const T*)nullptr, (const T*)nullptr,
        wt3, b3, s3, Pp, Pc, nullptr, nullptr, nullptr, 256, 256);  // x2 in P

    pool_k<T><<<(int)(PL3 / 256), blk, 0, stream>>>(Pp, Pc, Sp, Sc, 128, 128, (int)PL3);
    nconv_k<T, T, 32, 0, 5, false, false><<<g3, blk, 0, stream>>>(
        Sp, Sc, (long)(32 * HW3), (const T*)nullptr, (const T*)nullptr,
        wt2, b2, s2, Tp, Tc, nullptr, nullptr, nullptr, 128, 128);  // x3 in T

    pool_k<T><<<(int)(PL4 / 256), blk, 0, stream>>>(Tp, Tc, Up, Uc, 64, 64, (int)PL4);
    nconv_k<T, T, 32, 0, 5, false, false><<<g4, blk, 0, stream>>>(
        Up, Uc, (long)(32 * HW4), (const T*)nullptr, (const T*)nullptr,
        wt2, b2, s2, Vp, Vc, nullptr, nullptr, nullptr, 64, 64);    // x4 in V

    // decoder: cat(same-res, up2(half-res)) -> 3x3 nconv
    nconv_k<T, T, 32, 32, 3, false, false><<<g3, blk, 0, stream>>>(
        Tp, Tc, (long)(32 * HW3), Vp, Vc, wt4, b4, s4,
        Sp, Sc, nullptr, nullptr, nullptr, 128, 128);               // x34 in S
    nconv_k<T, T, 32, 32, 3, false, false><<<g2, blk, 0, stream>>>(
        Pp, Pc, (long)(32 * HW2), Sp, Sc, wt5, b5, s5,
        Qp, Qc, nullptr, nullptr, nullptr, 256, 256);               // x23 in Q
    // final: w6 conv (channel-swapped weights) + fused w7 1x1 nconv
    nconv_k<T, float, 32, 32, 3, false, true><<<g1, blk, 0, stream>>>(
        Ap, Ac, (long)(32 * HW1), Qp, Qc, wt6, b6, s6,
        (float*)nullptr, (float*)nullptr, w7, b7, dout, 512, 512);
}

// ---------------------------------------------------------------------------
extern "C" void kernel_launch(void* const* d_in, const int* in_sizes, int n_in,
                              void* d_out, int out_size, void* d_ws, size_t ws_size,
                              hipStream_t stream) {
    const float* x  = (const float*)d_in[0];
    const float* w1 = (const float*)d_in[1];
    const float* b1 = (const float*)d_in[2];
    const float* w2 = (const float*)d_in[3];
    const float* b2 = (const float*)d_in[4];
    const float* w3 = (const float*)d_in[5];
    const float* b3 = (const float*)d_in[6];
    const float* w4 = (const float*)d_in[7];
    const float* b4 = (const float*)d_in[8];
    const float* w5 = (const float*)d_in[9];
    const float* b5 = (const float*)d_in[10];
    const float* w6 = (const float*)d_in[11];
    const float* b6 = (const float*)d_in[12];
    const float* w7 = (const float*)d_in[13];
    const float* b7 = (const float*)d_in[14];

    // weight arena at start of ws (fp32, 107,488 floats used; reserve 440000 B)
    const size_t WARENA = 440000;
    float* wa = (float*)d_ws;
    float *wt1 = wa, *wt2 = wt1 + 800, *wt3 = wt2 + 25600;
    float *wt4 = wt3 + 25600, *wt5 = wt4 + 18432, *wt6 = wt5 + 18432;
    float *s1 = wt6 + 18432, *s2 = s1 + 32, *s3 = s2 + 32;
    float *s4 = s3 + 32, *s5 = s4 + 32, *s6 = s5 + 32;
    char* buf = (char*)d_ws + WARENA;

    const size_t HW1 = 512 * 512;
    auto need = [&](int NB, size_t esz) {
        return WARENA + 4ull * NB * 32 * HW1 * esz;
    };

    int NB; bool use_f32;
    if (ws_size >= need(2, 4))      { NB = 2; use_f32 = true;  }   // 269 MB
    else if (ws_size >= need(1, 4)) { NB = 1; use_f32 = true;  }   // 135 MB, 2 passes
    else if (ws_size >= need(1, 2)) { NB = 1; use_f32 = false; }   // 67.5 MB, 2 passes
    else return;  // clean fail: ws smaller than known-possible from round 2

    // weight prep (once)
    wsum_k<<<1, 32, 0, stream>>>(w1, s1, 25);
    wsum_k<<<1, 32, 0, stream>>>(w2, s2, 800);
    wsum_k<<<1, 32, 0, stream>>>(w3, s3, 800);
    wsum_k<<<1, 32, 0, stream>>>(w4, s4, 576);
    wsum_k<<<1, 32, 0, stream>>>(w5, s5, 576);
    wsum_k<<<1, 32, 0, stream>>>(w6, s6, 576);
    wtr_k<<<4, 256, 0, stream>>>(w1, wt1, 1, 25, 0);
    wtr_k<<<100, 256, 0, stream>>>(w2, wt2, 32, 25, 0);
    wtr_k<<<100, 256, 0, stream>>>(w3, wt3, 32, 25, 0);
    wtr_k<<<72, 256, 0, stream>>>(w4, wt4, 64, 9, 0);
    wtr_k<<<72, 256, 0, stream>>>(w5, wt5, 64, 9, 0);
    // w6: cat(x23_up, x1); kernel src1=x1 (rows 0..31), src2=x23_up (rows
    // 32..63); original w6 has x23_up first => swap halves (ci ^ 32).
    wtr_k<<<72, 256, 0, stream>>>(w6, wt6, 64, 9, 32);

    const int passes = 2 / NB;
    for (int p = 0; p < passes; ++p) {
        const float* xp = x + (size_t)p * NB * 2 * HW1;
        float* dp = (float*)d_out + (size_t)p * NB * HW1;
        if (use_f32)
            run_net<float>(xp, b1, b2, b3, b4, b5, b6, w7, b7,
                           wt1, wt2, wt3, wt4, wt5, wt6,
                           s1, s2, s3, s4, s5, s6, dp, (float*)buf, NB, stream);
        else
            run_net<__hip_bfloat16>(xp, b1, b2, b3, b4, b5, b6, w7, b7,
                                    wt1, wt2, wt3, wt4, wt5, wt6,
                                    s1, s2, s3, s4, s5, s6, dp,
                                    (__hip_bfloat16*)buf, NB, stream);
    }
}

// Round 4
// 912.423 us; speedup vs baseline: 8.3528x; 8.3528x over previous
//
#include <hip/hip_runtime.h>
#include <hip/hip_bf16.h>

#define EPSF 1e-20f

using short8  = __attribute__((ext_vector_type(8))) short;
using float4f = __attribute__((ext_vector_type(4))) float;

__device__ __forceinline__ unsigned short f2bf(float f) {
    __hip_bfloat16 h = __float2bfloat16(f);
    return __builtin_bit_cast(unsigned short, h);
}
__device__ __forceinline__ float bf2f(unsigned short u) {
    __hip_bfloat16 h = __builtin_bit_cast(__hip_bfloat16, u);
    return __bfloat162float(h);
}

// ---------------------------------------------------------------------------
// Weight prep.
// wsum: s[co] = sum over (ci,kh,kw) of original w.
// ---------------------------------------------------------------------------
__global__ void wsum_k(const float* __restrict__ w, float* __restrict__ s, int n) {
    int co = threadIdx.x;  // 32 threads
    float acc = 0.f;
    for (int i = 0; i < n; ++i) acc += w[co * n + i];
    s[co] = acc;
}

// conv1 weights transposed to [tap][co] (fp32, thread-uniform reads)
__global__ void wtr_k(const float* __restrict__ w, float* __restrict__ wt, int KK) {
    int idx = blockIdx.x * 256 + threadIdx.x;
    if (idx >= 32 * KK) return;
    int co = idx / KK, t = idx % KK;
    wt[t * 32 + co] = w[idx];
}

// MFMA A-operand fragments, bf16, in exact lane order:
//   wf[((ks*2+cot)*64 + lane)*8 + j] = w[co][ci][tap]
//   co = cot*16 + (lane&15);  ci = (phase*32 + (lane>>4)*8 + j) ^ cxor
//   ks = phase*KK + tap  (phase = ci-half for CIN=64)
__global__ void wfrag_k(const float* __restrict__ w, unsigned short* __restrict__ wf,
                        int CIN, int KK, int cxor, int total) {
    int idx = blockIdx.x * 256 + threadIdx.x;
    if (idx >= total) return;
    int j = idx & 7, lane = (idx >> 3) & 63, cot = (idx >> 9) & 1, ks = idx >> 10;
    int phase = ks / KK, tap = ks - phase * KK;
    int co = cot * 16 + (lane & 15);
    int ci = (phase * 32 + (lane >> 4) * 8 + j) ^ cxor;
    wf[idx] = f2bf(w[((long)co * CIN + ci) * KK + tap]);
}

// ---------------------------------------------------------------------------
// conv1: CIN=1 direct VALU conv (K too small for MFMA). Input x planar fp32
// [b][{data,conf}][H][W]; output channel-last bf16 [b*2+pc][pix][32ci].
// ---------------------------------------------------------------------------
__global__ __launch_bounds__(256)
void conv1_k(const float* __restrict__ x, const float* __restrict__ wt,
             const float* __restrict__ bias, const float* __restrict__ sden,
             unsigned short* __restrict__ out, int H, int W) {
    const int tx = threadIdx.x & 31, ty = threadIdx.x >> 5;
    const int xx = blockIdx.x * 32 + tx, yy = blockIdx.y * 8 + ty, b = blockIdx.z;
    const long HW = (long)H * W;
    float ac[32], ap[32];
#pragma unroll
    for (int i = 0; i < 32; ++i) { ac[i] = 0.f; ap[i] = 0.f; }
    const float* xd = x + (long)(b * 2) * HW;
    const float* xc = xd + HW;
#pragma unroll
    for (int dy = 0; dy < 5; ++dy) {
#pragma unroll
        for (int dx = 0; dx < 5; ++dx) {
            int r = yy + dy - 2, c = xx + dx - 2;
            bool v = (r >= 0) & (r < H) & (c >= 0) & (c < W);
            int off = v ? (r * W + c) : 0;
            float cf = v ? xc[off] : 0.f;
            float pv = (v ? xd[off] : 0.f) * cf;
            const float* wr = wt + (dy * 5 + dx) * 32;
#pragma unroll
            for (int co = 0; co < 32; ++co) {
                ac[co] = fmaf(wr[co], cf, ac[co]);
                ap[co] = fmaf(wr[co], pv, ap[co]);
            }
        }
    }
    unsigned short* po = out + ((long)(b * 2 + 0) * HW + (long)yy * W + xx) * 32;
    unsigned short* co_ = out + ((long)(b * 2 + 1) * HW + (long)yy * W + xx) * 32;
#pragma unroll
    for (int g = 0; g < 4; ++g) {
        uint4 vp, vc;
        unsigned int pw[4], cw[4];
#pragma unroll
        for (int h = 0; h < 4; ++h) {
            int c0 = g * 8 + h * 2, c1 = c0 + 1;
            float d0 = ac[c0], d1 = ac[c1];
            float ox0 = ap[c0] / (d0 + EPSF) + bias[c0];
            float ox1 = ap[c1] / (d1 + EPSF) + bias[c1];
            float oc0 = d0 / sden[c0], oc1 = d1 / sden[c1];
            pw[h] = (unsigned int)f2bf(ox0 * oc0) | ((unsigned int)f2bf(ox1 * oc1) << 16);
            cw[h] = (unsigned int)f2bf(oc0) | ((unsigned int)f2bf(oc1) << 16);
        }
        vp.x = pw[0]; vp.y = pw[1]; vp.z = pw[2]; vp.w = pw[3];
        vc.x = cw[0]; vc.y = cw[1]; vc.z = cw[2]; vc.w = cw[3];
        *(uint4*)(po + g * 8) = vp;
        *(uint4*)(co_ + g * 8) = vc;
    }
}

// ---------------------------------------------------------------------------
// MFMA implicit-GEMM nconv.
//  - channel-last bf16 storage [b*2+pc][y][x][32ci]
//  - per tap: K = 32 ci in ONE 16x16x32 mfma k-step
//  - A = weights (M = co, fragment-ordered global buffer, L1-resident)
//  - B = pixels from LDS tile (halo-padded, zero-filled at image edges)
//  - D: col = lane&15 = pixel, row = (lane>>4)*4+reg = co  [m89-verified]
//  - NPH=2: second phase stages src2 (half-res, nearest-up2'd in staging)
//  - FUSE7: fuse final 1x1 nconv (w7,b7), write fp32 xout
// Block: 256 thr = 4 waves; out tile 32x8; wave = 2 rows x 32 px = 4 m-tiles.
// ---------------------------------------------------------------------------
template <int KS, int NPH, bool FUSE7>
__global__ __launch_bounds__(256, 2)
void mconv_k(const unsigned short* __restrict__ s1,
             const unsigned short* __restrict__ s2,
             const unsigned short* __restrict__ wf,
             const float* __restrict__ bias, const float* __restrict__ sden,
             unsigned short* __restrict__ out, float* __restrict__ xout,
             const float* __restrict__ w7, const float* __restrict__ b7,
             int H, int W) {
    constexpr int R = KS / 2, KK = KS * KS;
    constexpr int TIH = 8 + KS - 1, TIW = 32 + KS - 1;
    constexpr int PCS = TIH * TIW * 32;        // ushorts per pc-plane
    constexpr int NCH = TIH * TIW * 4;         // 16B chunks per pc-plane
    __shared__ unsigned short lds[2 * PCS];

    const int tid = threadIdx.x;
    const int wv = tid >> 6, lane = tid & 63, n = lane & 15, q = lane >> 4;
    const int ox0 = blockIdx.x * 32, oy0 = blockIdx.y * 8, b = blockIdx.z;
    const long HW = (long)H * W;

    float4f accP[4][2], accC[4][2];
#pragma unroll
    for (int mt = 0; mt < 4; ++mt)
#pragma unroll
        for (int ct = 0; ct < 2; ++ct) {
            accP[mt][ct] = (float4f)0.f;
            accC[mt][ct] = (float4f)0.f;
        }

    const int B0 = n * 32 + q * 8 + wv * (2 * TIW * 32);

    for (int ph = 0; ph < NPH; ++ph) {
        const unsigned short* src = (NPH == 2 && ph == 1) ? s2 : s1;
        __syncthreads();  // protect LDS from prior-phase readers
        // ---- stage tile (both pc planes) into LDS, zero-padded ----
        for (int it = 0; it < (2 * NCH + 255) / 256; ++it) {
            int ch = it * 256 + tid;
            if (ch < 2 * NCH) {
                int pc = ch / NCH, c2 = ch - pc * NCH;
                int pix = c2 >> 2, k8 = c2 & 3;
                int py = pix / TIW, px = pix - py * TIW;
                int gy = oy0 - R + py, gx = ox0 - R + px;
                uint4 v = make_uint4(0, 0, 0, 0);
                if (gy >= 0 && gy < H && gx >= 0 && gx < W) {
                    long gi;
                    if (NPH == 2 && ph == 1)
                        gi = ((long)(b * 2 + pc) * (HW >> 2) +
                              (long)(gy >> 1) * (W >> 1) + (gx >> 1)) * 32 + k8 * 8;
                    else
                        gi = ((long)(b * 2 + pc) * HW + (long)gy * W + gx) * 32 + k8 * 8;
                    v = *(const uint4*)(src + gi);
                }
                *(uint4*)(lds + pc * PCS + pix * 32 + k8 * 8) = v;
            }
        }
        __syncthreads();
        // ---- tap loop: one mfma k-step per tap per (mt, cot, plane) ----
#pragma unroll
        for (int dy = 0; dy < KS; ++dy) {
#pragma unroll
            for (int dx = 0; dx < KS; ++dx) {
                const int ks = ph * KK + dy * KS + dx;
                short8 a0 = ((const short8*)wf)[(ks * 2 + 0) * 64 + lane];
                short8 a1 = ((const short8*)wf)[(ks * 2 + 1) * 64 + lane];
#pragma unroll
                for (int mt = 0; mt < 4; ++mt) {
                    const int off = B0 + ((mt >> 1) + dy) * (TIW * 32) +
                                    ((mt & 1) * 16 + dx) * 32;
                    short8 bp = *(const short8*)(lds + off);
                    short8 bc = *(const short8*)(lds + off + PCS);
                    accP[mt][0] = __builtin_amdgcn_mfma_f32_16x16x32_bf16(a0, bp, accP[mt][0], 0, 0, 0);
                    accP[mt][1] = __builtin_amdgcn_mfma_f32_16x16x32_bf16(a1, bp, accP[mt][1], 0, 0, 0);
                    accC[mt][0] = __builtin_amdgcn_mfma_f32_16x16x32_bf16(a0, bc, accC[mt][0], 0, 0, 0);
                    accC[mt][1] = __builtin_amdgcn_mfma_f32_16x16x32_bf16(a1, bc, accC[mt][1], 0, 0, 0);
                }
            }
        }
    }

    // ---- epilogue ----
    float4f b4[2], s4[2];
    b4[0] = *(const float4f*)(bias + q * 4);
    b4[1] = *(const float4f*)(bias + 16 + q * 4);
    s4[0] = *(const float4f*)(sden + q * 4);
    s4[1] = *(const float4f*)(sden + 16 + q * 4);

    if (!FUSE7) {
#pragma unroll
        for (int mt = 0; mt < 4; ++mt) {
            const int oy = oy0 + wv * 2 + (mt >> 1);
            const int ox = ox0 + (mt & 1) * 16 + n;
            const long pixb = ((long)oy * W + ox) * 32;
#pragma unroll
            for (int ct = 0; ct < 2; ++ct) {
                unsigned int pw[2], cw[2];
#pragma unroll
                for (int h = 0; h < 2; ++h) {
                    float d0 = accC[mt][ct][h * 2], d1 = accC[mt][ct][h * 2 + 1];
                    float ox0v = accP[mt][ct][h * 2] / (d0 + EPSF) + b4[ct][h * 2];
                    float ox1v = accP[mt][ct][h * 2 + 1] / (d1 + EPSF) + b4[ct][h * 2 + 1];
                    float oc0 = d0 / s4[ct][h * 2], oc1 = d1 / s4[ct][h * 2 + 1];
                    pw[h] = (unsigned int)f2bf(ox0v * oc0) | ((unsigned int)f2bf(ox1v * oc1) << 16);
                    cw[h] = (unsigned int)f2bf(oc0) | ((unsigned int)f2bf(oc1) << 16);
                }
                uint2 vp; vp.x = pw[0]; vp.y = pw[1];
                uint2 vc; vc.x = cw[0]; vc.y = cw[1];
                long ip = (long)(b * 2 + 0) * HW * 32 + pixb + ct * 16 + q * 4;
                long ic = (long)(b * 2 + 1) * HW * 32 + pixb + ct * 16 + q * 4;
                *(uint2*)(out + ip) = vp;
                *(uint2*)(out + ic) = vc;
            }
        }
    } else {
        float4f w74[2];
        w74[0] = *(const float4f*)(w7 + q * 4);
        w74[1] = *(const float4f*)(w7 + 16 + q * 4);
        const float b7v = b7[0];
#pragma unroll
        for (int mt = 0; mt < 4; ++mt) {
            float num = 0.f, den = 0.f;
#pragma unroll
            for (int ct = 0; ct < 2; ++ct)
#pragma unroll
                for (int r = 0; r < 4; ++r) {
                    float d = accC[mt][ct][r];
                    float oxv = accP[mt][ct][r] / (d + EPSF) + b4[ct][r];
                    float oc = d / s4[ct][r];
                    num = fmaf(w74[ct][r], oxv * oc, num);
                    den = fmaf(w74[ct][r], oc, den);
                }
            num += __shfl_xor(num, 16); num += __shfl_xor(num, 32);
            den += __shfl_xor(den, 16); den += __shfl_xor(den, 32);
            if (q == 0) {
                const int oy = oy0 + wv * 2 + (mt >> 1);
                const int ox = ox0 + (mt & 1) * 16 + n;
                xout[(long)b * HW + (long)oy * W + ox] = num / (den + EPSF) + b7v;
            }
        }
    }
}

// ---------------------------------------------------------------------------
// 2x2 stride-2 pool on channel-last layout: per (b, out-pixel, 8-ci chunk),
// per-ci argmax of c (first-max, row-major), gather p; both * 0.25.
// ---------------------------------------------------------------------------
__global__ void pool_k(const unsigned short* __restrict__ in, unsigned short* __restrict__ out,
                       int H2, int W2, int total) {
    int idx = blockIdx.x * 256 + threadIdx.x;
    if (idx >= total) return;
    int k8 = idx & 3, t = idx >> 2;
    long HW2 = (long)H2 * W2;
    int pix2 = (int)(t % HW2), b = (int)(t / HW2);
    int h = pix2 / W2, w = pix2 - h * W2;
    int W = W2 * 2;
    long HW = HW2 * 4;
    long p00 = ((long)(2 * h) * W + 2 * w) * 32 + k8 * 8;
    const unsigned short* pin = in + (long)(b * 2 + 0) * HW * 32;
    const unsigned short* cin = in + (long)(b * 2 + 1) * HW * 32;
    union U { uint4 v; unsigned short s[8]; };
    U c0, c1, c2, c3, p0, p1, p2, p3, rp, rc;
    c0.v = *(const uint4*)(cin + p00);             c1.v = *(const uint4*)(cin + p00 + 32);
    c2.v = *(const uint4*)(cin + p00 + (long)W * 32); c3.v = *(const uint4*)(cin + p00 + (long)W * 32 + 32);
    p0.v = *(const uint4*)(pin + p00);             p1.v = *(const uint4*)(pin + p00 + 32);
    p2.v = *(const uint4*)(pin + p00 + (long)W * 32); p3.v = *(const uint4*)(pin + p00 + (long)W * 32 + 32);
#pragma unroll
    for (int e = 0; e < 8; ++e) {
        float cv = bf2f(c0.s[e]), pv = bf2f(p0.s[e]);
        float c01 = bf2f(c1.s[e]); if (c01 > cv) { cv = c01; pv = bf2f(p1.s[e]); }
        float c10 = bf2f(c2.s[e]); if (c10 > cv) { cv = c10; pv = bf2f(p2.s[e]); }
        float c11 = bf2f(c3.s[e]); if (c11 > cv) { cv = c11; pv = bf2f(p3.s[e]); }
        rp.s[e] = f2bf(pv * 0.25f);
        rc.s[e] = f2bf(cv * 0.25f);
    }
    long ob = ((long)pix2) * 32 + k8 * 8;
    *(uint4*)(out + (long)(b * 2 + 0) * HW2 * 32 + ob) = rp.v;
    *(uint4*)(out + (long)(b * 2 + 1) * HW2 * 32 + ob) = rc.v;
}

// ---------------------------------------------------------------------------
extern "C" void kernel_launch(void* const* d_in, const int* in_sizes, int n_in,
                              void* d_out, int out_size, void* d_ws, size_t ws_size,
                              hipStream_t stream) {
    const float* x  = (const float*)d_in[0];
    const float* w1 = (const float*)d_in[1];
    const float* b1 = (const float*)d_in[2];
    const float* w2 = (const float*)d_in[3];
    const float* b2 = (const float*)d_in[4];
    const float* w3 = (const float*)d_in[5];
    const float* b3 = (const float*)d_in[6];
    const float* w4 = (const float*)d_in[7];
    const float* b4 = (const float*)d_in[8];
    const float* w5 = (const float*)d_in[9];
    const float* b5 = (const float*)d_in[10];
    const float* w6 = (const float*)d_in[11];
    const float* b6 = (const float*)d_in[12];
    const float* w7 = (const float*)d_in[13];
    const float* b7 = (const float*)d_in[14];

    const size_t HW1 = 512 * 512, HW2s = 256 * 256, HW3s = 128 * 128, HW4s = 64 * 64;

    // ---- weight arena (400000 B) ----
    const size_t WARENA = 400000;
    float* fa = (float*)d_ws;
    float *wt1 = fa;                 // 800 f
    float *s1 = wt1 + 800, *s2 = s1 + 32, *s3 = s2 + 32;
    float *s4 = s3 + 32, *s5 = s4 + 32, *s6 = s5 + 32;   // ends at 992 f = 3968 B
    unsigned short* ua = (unsigned short*)((char*)d_ws + 4096);
    unsigned short *wf2 = ua;              // 25600
    unsigned short *wf3 = wf2 + 25600;     // 25600
    unsigned short *wf4 = wf3 + 25600;     // 18432
    unsigned short *wf5 = wf4 + 18432;     // 18432
    unsigned short *wf6 = wf5 + 18432;     // 18432 -> total 213 KB < 400000-4096
    unsigned short* buf = (unsigned short*)((char*)d_ws + WARENA);

    // ---- stage buffers: channel-last bf16 [b*2+pc][HW][32] ----
    const size_t E1 = 2 * 2 * HW1 * 32;    // 33.55M ushort = 67.1 MB
    const size_t E2 = 2 * 2 * HW2s * 32, E3 = 2 * 2 * HW3s * 32, E4 = 2 * 2 * HW4s * 32;
    unsigned short* A = buf;
    unsigned short* B = A + E1;
    // lower-res alias inside B (sum = 22M ushorts <= E1)
    unsigned short* P = B;
    unsigned short* Q = P + E2;
    unsigned short* S = Q + E2;
    unsigned short* T = S + E3;
    unsigned short* U = T + E3;
    unsigned short* V = U + E4;

    if (ws_size < WARENA + 2 * E1 * sizeof(unsigned short)) return;  // 134.62 MB

    // ---- weight prep ----
    wsum_k<<<1, 32, 0, stream>>>(w1, s1, 25);
    wsum_k<<<1, 32, 0, stream>>>(w2, s2, 800);
    wsum_k<<<1, 32, 0, stream>>>(w3, s3, 800);
    wsum_k<<<1, 32, 0, stream>>>(w4, s4, 576);
    wsum_k<<<1, 32, 0, stream>>>(w5, s5, 576);
    wsum_k<<<1, 32, 0, stream>>>(w6, s6, 576);
    wtr_k<<<4, 256, 0, stream>>>(w1, wt1, 25);
    wfrag_k<<<100, 256, 0, stream>>>(w2, wf2, 32, 25, 0, 25600);
    wfrag_k<<<100, 256, 0, stream>>>(w3, wf3, 32, 25, 0, 25600);
    wfrag_k<<<72, 256, 0, stream>>>(w4, wf4, 64, 9, 0, 18432);
    wfrag_k<<<72, 256, 0, stream>>>(w5, wf5, 64, 9, 0, 18432);
    // w6: device phase0 = x1 (orig ci 32..63), phase1 = x23_up (orig 0..31)
    wfrag_k<<<72, 256, 0, stream>>>(w6, wf6, 64, 9, 32, 18432);

    dim3 blk(256);
    dim3 g1(16, 64, 2), g2(8, 32, 2), g3(4, 16, 2), g4(2, 8, 2);

    // ---- encoder ----
    conv1_k<<<g1, blk, 0, stream>>>(x, wt1, b1, s1, A, 512, 512);
    mconv_k<5, 1, false><<<g1, blk, 0, stream>>>(A, nullptr, wf2, b2, s2, B, nullptr, nullptr, nullptr, 512, 512);
    mconv_k<5, 1, false><<<g1, blk, 0, stream>>>(B, nullptr, wf3, b3, s3, A, nullptr, nullptr, nullptr, 512, 512);  // x1 in A

    pool_k<<<(int)(2 * HW2s * 4 * 2 / 256), blk, 0, stream>>>(A, P, 256, 256, (int)(2 * HW2s * 4));
    mconv_k<5, 1, false><<<g2, blk, 0, stream>>>(P, nullptr, wf2, b2, s2, Q, nullptr, nullptr, nullptr, 256, 256);
    mconv_k<5, 1, false><<<g2, blk, 0, stream>>>(Q, nullptr, wf3, b3, s3, P, nullptr, nullptr, nullptr, 256, 256);  // x2 in P

    pool_k<<<(int)(2 * HW3s * 4 * 2 / 256), blk, 0, stream>>>(P, S, 128, 128, (int)(2 * HW3s * 4));
    mconv_k<5, 1, false><<<g3, blk, 0, stream>>>(S, nullptr, wf2, b2, s2, T, nullptr, nullptr, nullptr, 128, 128);  // x3 in T

    pool_k<<<(int)(2 * HW4s * 4 * 2 / 256), blk, 0, stream>>>(T, U, 64, 64, (int)(2 * HW4s * 4));
    mconv_k<5, 1, false><<<g4, blk, 0, stream>>>(U, nullptr, wf2, b2, s2, V, nullptr, nullptr, nullptr, 64, 64);    // x4 in V

    // ---- decoder ----
    mconv_k<3, 2, false><<<g3, blk, 0, stream>>>(T, V, wf4, b4, s4, S, nullptr, nullptr, nullptr, 128, 128);        // x34 in S
    mconv_k<3, 2, false><<<g2, blk, 0, stream>>>(P, S, wf5, b5, s5, Q, nullptr, nullptr, nullptr, 256, 256);        // x23 in Q
    mconv_k<3, 2, true><<<g1, blk, 0, stream>>>(A, Q, wf6, b6, s6, nullptr, (float*)d_out, w7, b7, 512, 512);
}

// Round 5
// 547.501 us; speedup vs baseline: 13.9202x; 1.6665x over previous
//
#include <hip/hip_runtime.h>
#include <hip/hip_bf16.h>

#define EPSF 1e-20f

using short8  = __attribute__((ext_vector_type(8))) short;
using float4f = __attribute__((ext_vector_type(4))) float;

__device__ __forceinline__ unsigned short f2bf(float f) {
    __hip_bfloat16 h = __float2bfloat16(f);
    return __builtin_bit_cast(unsigned short, h);
}
__device__ __forceinline__ float bf2f(unsigned short u) {
    __hip_bfloat16 h = __builtin_bit_cast(__hip_bfloat16, u);
    return __bfloat162float(h);
}
__device__ __forceinline__ float frcp(float x) { return __builtin_amdgcn_rcpf(x); }

// ---------------------------------------------------------------------------
// Unified weight prep (one launch):
//  [0,800)      : conv1 weights -> wt1[tap*32+co] (fp32)
//  [800,992)    : 6 weight sums -> store RECIPROCAL 1/sum
//  [992,107488) : MFMA A-fragments for w2..w6 (bf16, lane-exact order)
//    wf[((ks*2+cot)*64+lane)*8+j] = w[co][ci][tap],
//    co = cot*16+(lane&15); ci = (phase*32+(lane>>4)*8+j)^cxor; ks=phase*KK+tap
// ---------------------------------------------------------------------------
__global__ void wprep_k(const float* __restrict__ w1, const float* __restrict__ w2,
                        const float* __restrict__ w3, const float* __restrict__ w4,
                        const float* __restrict__ w5, const float* __restrict__ w6,
                        float* __restrict__ wt1,
                        float* __restrict__ is1, float* __restrict__ is2,
                        float* __restrict__ is3, float* __restrict__ is4,
                        float* __restrict__ is5, float* __restrict__ is6,
                        unsigned short* __restrict__ wf2, unsigned short* __restrict__ wf3,
                        unsigned short* __restrict__ wf4, unsigned short* __restrict__ wf5,
                        unsigned short* __restrict__ wf6) {
    int idx = blockIdx.x * 256 + threadIdx.x;
    if (idx < 800) {                       // conv1 transpose [tap][co]
        int co = idx / 25, t = idx % 25;
        wt1[t * 32 + co] = w1[idx];
        return;
    }
    if (idx < 992) {                       // reciprocal weight sums
        int j = idx - 800, task = j >> 5, co = j & 31;
        const float* w; int n; float* s;
        switch (task) {
            case 0: w = w1; n = 25;  s = is1; break;
            case 1: w = w2; n = 800; s = is2; break;
            case 2: w = w3; n = 800; s = is3; break;
            case 3: w = w4; n = 576; s = is4; break;
            case 4: w = w5; n = 576; s = is5; break;
            default: w = w6; n = 576; s = is6; break;
        }
        float acc = 0.f;
        for (int i = 0; i < n; ++i) acc += w[co * n + i];
        s[co] = 1.0f / acc;
        return;
    }
    int r = idx - 992;
    const float* w; unsigned short* wf; int CIN, KK, cxor;
    if (r < 25600)        {             w = w2; wf = wf2; CIN = 32; KK = 25; cxor = 0;  }
    else if (r < 51200)   { r -= 25600; w = w3; wf = wf3; CIN = 32; KK = 25; cxor = 0;  }
    else if (r < 69632)   { r -= 51200; w = w4; wf = wf4; CIN = 64; KK = 9;  cxor = 0;  }
    else if (r < 88064)   { r -= 69632; w = w5; wf = wf5; CIN = 64; KK = 9;  cxor = 0;  }
    else if (r < 106496)  { r -= 88064; w = w6; wf = wf6; CIN = 64; KK = 9;  cxor = 32; }
    else return;
    int j = r & 7, lane = (r >> 3) & 63, cot = (r >> 9) & 1, ks = r >> 10;
    int phase = ks / KK, tap = ks - phase * KK;
    int co = cot * 16 + (lane & 15);
    int ci = (phase * 32 + (lane >> 4) * 8 + j) ^ cxor;
    wf[r] = f2bf(w[((long)co * CIN + ci) * KK + tap]);
}

// ---------------------------------------------------------------------------
// conv1: CIN=1 direct VALU conv. Input planar fp32 [b][{data,conf}][H][W];
// output channel-last bf16 [b*2+pc][pix][32ci]. is_ = reciprocal weight sums.
// ---------------------------------------------------------------------------
__global__ __launch_bounds__(256)
void conv1_k(const float* __restrict__ x, const float* __restrict__ wt,
             const float* __restrict__ bias, const float* __restrict__ is_,
             unsigned short* __restrict__ out, int H, int W) {
    const int tx = threadIdx.x & 31, ty = threadIdx.x >> 5;
    const int xx = blockIdx.x * 32 + tx, yy = blockIdx.y * 8 + ty, b = blockIdx.z;
    const long HW = (long)H * W;
    float ac[32], ap[32];
#pragma unroll
    for (int i = 0; i < 32; ++i) { ac[i] = 0.f; ap[i] = 0.f; }
    const float* xd = x + (long)(b * 2) * HW;
    const float* xc = xd + HW;
#pragma unroll
    for (int dy = 0; dy < 5; ++dy) {
#pragma unroll
        for (int dx = 0; dx < 5; ++dx) {
            int r = yy + dy - 2, c = xx + dx - 2;
            bool v = (r >= 0) & (r < H) & (c >= 0) & (c < W);
            int off = v ? (r * W + c) : 0;
            float cf = v ? xc[off] : 0.f;
            float pv = (v ? xd[off] : 0.f) * cf;
            const float* wr = wt + (dy * 5 + dx) * 32;
#pragma unroll
            for (int co = 0; co < 32; ++co) {
                ac[co] = fmaf(wr[co], cf, ac[co]);
                ap[co] = fmaf(wr[co], pv, ap[co]);
            }
        }
    }
    unsigned short* po = out + ((long)(b * 2 + 0) * HW + (long)yy * W + xx) * 32;
    unsigned short* co_ = out + ((long)(b * 2 + 1) * HW + (long)yy * W + xx) * 32;
#pragma unroll
    for (int g = 0; g < 4; ++g) {
        uint4 vp, vc;
        unsigned int pw[4], cw[4];
#pragma unroll
        for (int h = 0; h < 4; ++h) {
            int c0 = g * 8 + h * 2, c1 = c0 + 1;
            float d0 = ac[c0], d1 = ac[c1];
            float ox0 = fmaf(ap[c0], frcp(d0 + EPSF), bias[c0]);
            float ox1 = fmaf(ap[c1], frcp(d1 + EPSF), bias[c1]);
            float oc0 = d0 * is_[c0], oc1 = d1 * is_[c1];
            pw[h] = (unsigned int)f2bf(ox0 * oc0) | ((unsigned int)f2bf(ox1 * oc1) << 16);
            cw[h] = (unsigned int)f2bf(oc0) | ((unsigned int)f2bf(oc1) << 16);
        }
        vp.x = pw[0]; vp.y = pw[1]; vp.z = pw[2]; vp.w = pw[3];
        vc.x = cw[0]; vc.y = cw[1]; vc.z = cw[2]; vc.w = cw[3];
        *(uint4*)(po + g * 8) = vp;
        *(uint4*)(co_ + g * 8) = vc;
    }
}

// ---------------------------------------------------------------------------
// MFMA implicit-GEMM nconv (channel-last bf16 [b*2+pc][y][x][32ci]).
// Per tap: K=32 ci in one 16x16x32 k-step. A = fragment-ordered weights,
// B = pixels from halo-padded LDS tile. D: col=lane&15=pixel,
// row=(lane>>4)*4+reg=co. NPH=2 stages src2 (half-res, up2'd in staging).
// FUSE7 fuses the final 1x1 nconv. is_ (sden) = reciprocal sums.
// Block: 256 thr = 4 waves; out tile 32x8; wave = 2 rows x 32 px.
// ---------------------------------------------------------------------------
template <int KS, int NPH, bool FUSE7>
__global__ __launch_bounds__(256, 2)
void mconv_k(const unsigned short* __restrict__ s1,
             const unsigned short* __restrict__ s2,
             const unsigned short* __restrict__ wf,
             const float* __restrict__ bias, const float* __restrict__ sden,
             unsigned short* __restrict__ out, float* __restrict__ xout,
             const float* __restrict__ w7, const float* __restrict__ b7,
             int H, int W) {
    constexpr int R = KS / 2, KK = KS * KS;
    constexpr int TIH = 8 + KS - 1, TIW = 32 + KS - 1;
    constexpr int PCS = TIH * TIW * 32;        // ushorts per pc-plane
    constexpr int NCH = TIH * TIW * 4;         // 16B chunks per pc-plane
    __shared__ unsigned short lds[2 * PCS];

    const int tid = threadIdx.x;
    const int wv = tid >> 6, lane = tid & 63, n = lane & 15, q = lane >> 4;
    const int ox0 = blockIdx.x * 32, oy0 = blockIdx.y * 8, b = blockIdx.z;
    const long HW = (long)H * W;

    float4f accP[4][2], accC[4][2];
#pragma unroll
    for (int mt = 0; mt < 4; ++mt)
#pragma unroll
        for (int ct = 0; ct < 2; ++ct) {
            accP[mt][ct] = (float4f)0.f;
            accC[mt][ct] = (float4f)0.f;
        }

    const int B0 = n * 32 + q * 8 + wv * (2 * TIW * 32);

    for (int ph = 0; ph < NPH; ++ph) {
        const unsigned short* src = (NPH == 2 && ph == 1) ? s2 : s1;
        __syncthreads();  // protect LDS from prior-phase readers
        // ---- stage tile (both pc planes) into LDS, zero-padded ----
        for (int it = 0; it < (2 * NCH + 255) / 256; ++it) {
            int ch = it * 256 + tid;
            if (ch < 2 * NCH) {
                int pc = ch / NCH, c2 = ch - pc * NCH;
                int pix = c2 >> 2, k8 = c2 & 3;
                int py = pix / TIW, px = pix - py * TIW;
                int gy = oy0 - R + py, gx = ox0 - R + px;
                uint4 v = make_uint4(0, 0, 0, 0);
                if (gy >= 0 && gy < H && gx >= 0 && gx < W) {
                    long gi;
                    if (NPH == 2 && ph == 1)
                        gi = ((long)(b * 2 + pc) * (HW >> 2) +
                              (long)(gy >> 1) * (W >> 1) + (gx >> 1)) * 32 + k8 * 8;
                    else
                        gi = ((long)(b * 2 + pc) * HW + (long)gy * W + gx) * 32 + k8 * 8;
                    v = *(const uint4*)(src + gi);
                }
                *(uint4*)(lds + pc * PCS + pix * 32 + k8 * 8) = v;
            }
        }
        __syncthreads();
        // ---- tap loop: one mfma k-step per tap per (mt, cot, plane) ----
#pragma unroll
        for (int dy = 0; dy < KS; ++dy) {
#pragma unroll
            for (int dx = 0; dx < KS; ++dx) {
                const int ks = ph * KK + dy * KS + dx;
                short8 a0 = ((const short8*)wf)[(ks * 2 + 0) * 64 + lane];
                short8 a1 = ((const short8*)wf)[(ks * 2 + 1) * 64 + lane];
#pragma unroll
                for (int mt = 0; mt < 4; ++mt) {
                    const int off = B0 + ((mt >> 1) + dy) * (TIW * 32) +
                                    ((mt & 1) * 16 + dx) * 32;
                    short8 bp = *(const short8*)(lds + off);
                    short8 bc = *(const short8*)(lds + off + PCS);
                    accP[mt][0] = __builtin_amdgcn_mfma_f32_16x16x32_bf16(a0, bp, accP[mt][0], 0, 0, 0);
                    accP[mt][1] = __builtin_amdgcn_mfma_f32_16x16x32_bf16(a1, bp, accP[mt][1], 0, 0, 0);
                    accC[mt][0] = __builtin_amdgcn_mfma_f32_16x16x32_bf16(a0, bc, accC[mt][0], 0, 0, 0);
                    accC[mt][1] = __builtin_amdgcn_mfma_f32_16x16x32_bf16(a1, bc, accC[mt][1], 0, 0, 0);
                }
            }
        }
    }

    // ---- epilogue ----
    float4f b4[2], s4[2];
    b4[0] = *(const float4f*)(bias + q * 4);
    b4[1] = *(const float4f*)(bias + 16 + q * 4);
    s4[0] = *(const float4f*)(sden + q * 4);
    s4[1] = *(const float4f*)(sden + 16 + q * 4);

    if (!FUSE7) {
#pragma unroll
        for (int mt = 0; mt < 4; ++mt) {
            const int oy = oy0 + wv * 2 + (mt >> 1);
            const int ox = ox0 + (mt & 1) * 16 + n;
            const long pixb = ((long)oy * W + ox) * 32;
#pragma unroll
            for (int ct = 0; ct < 2; ++ct) {
                unsigned int pw[2], cw[2];
#pragma unroll
                for (int h = 0; h < 2; ++h) {
                    float d0 = accC[mt][ct][h * 2], d1 = accC[mt][ct][h * 2 + 1];
                    float ox0v = fmaf(accP[mt][ct][h * 2], frcp(d0 + EPSF), b4[ct][h * 2]);
                    float ox1v = fmaf(accP[mt][ct][h * 2 + 1], frcp(d1 + EPSF), b4[ct][h * 2 + 1]);
                    float oc0 = d0 * s4[ct][h * 2], oc1 = d1 * s4[ct][h * 2 + 1];
                    pw[h] = (unsigned int)f2bf(ox0v * oc0) | ((unsigned int)f2bf(ox1v * oc1) << 16);
                    cw[h] = (unsigned int)f2bf(oc0) | ((unsigned int)f2bf(oc1) << 16);
                }
                uint2 vp; vp.x = pw[0]; vp.y = pw[1];
                uint2 vc; vc.x = cw[0]; vc.y = cw[1];
                long ip = (long)(b * 2 + 0) * HW * 32 + pixb + ct * 16 + q * 4;
                long ic = (long)(b * 2 + 1) * HW * 32 + pixb + ct * 16 + q * 4;
                *(uint2*)(out + ip) = vp;
                *(uint2*)(out + ic) = vc;
            }
        }
    } else {
        float4f w74[2];
        w74[0] = *(const float4f*)(w7 + q * 4);
        w74[1] = *(const float4f*)(w7 + 16 + q * 4);
        const float b7v = b7[0];
#pragma unroll
        for (int mt = 0; mt < 4; ++mt) {
            float num = 0.f, den = 0.f;
#pragma unroll
            for (int ct = 0; ct < 2; ++ct)
#pragma unroll
                for (int r = 0; r < 4; ++r) {
                    float d = accC[mt][ct][r];
                    float oxv = fmaf(accP[mt][ct][r], frcp(d + EPSF), b4[ct][r]);
                    float oc = d * s4[ct][r];
                    num = fmaf(w74[ct][r], oxv * oc, num);
                    den = fmaf(w74[ct][r], oc, den);
                }
            num += __shfl_xor(num, 16); num += __shfl_xor(num, 32);
            den += __shfl_xor(den, 16); den += __shfl_xor(den, 32);
            if (q == 0) {
                const int oy = oy0 + wv * 2 + (mt >> 1);
                const int ox = ox0 + (mt & 1) * 16 + n;
                xout[(long)b * HW + (long)oy * W + ox] = fmaf(num, frcp(den + EPSF), b7v);
            }
        }
    }
}

// ---------------------------------------------------------------------------
// 2x2 stride-2 pool on channel-last layout: per (b, out-pixel, 8-ci chunk),
// per-ci argmax of c (first-max, row-major), gather p; both * 0.25.
// ---------------------------------------------------------------------------
__global__ void pool_k(const unsigned short* __restrict__ in, unsigned short* __restrict__ out,
                       int H2, int W2, int total) {
    int idx = blockIdx.x * 256 + threadIdx.x;
    if (idx >= total) return;
    int k8 = idx & 3, t = idx >> 2;
    long HW2 = (long)H2 * W2;
    int pix2 = (int)(t % HW2), b = (int)(t / HW2);
    int h = pix2 / W2, w = pix2 - h * W2;
    int W = W2 * 2;
    long HW = HW2 * 4;
    long p00 = ((long)(2 * h) * W + 2 * w) * 32 + k8 * 8;
    const unsigned short* pin = in + (long)(b * 2 + 0) * HW * 32;
    const unsigned short* cin = in + (long)(b * 2 + 1) * HW * 32;
    union U { uint4 v; unsigned short s[8]; };
    U c0, c1, c2, c3, p0, p1, p2, p3, rp, rc;
    c0.v = *(const uint4*)(cin + p00);             c1.v = *(const uint4*)(cin + p00 + 32);
    c2.v = *(const uint4*)(cin + p00 + (long)W * 32); c3.v = *(const uint4*)(cin + p00 + (long)W * 32 + 32);
    p0.v = *(const uint4*)(pin + p00);             p1.v = *(const uint4*)(pin + p00 + 32);
    p2.v = *(const uint4*)(pin + p00 + (long)W * 32); p3.v = *(const uint4*)(pin + p00 + (long)W * 32 + 32);
#pragma unroll
    for (int e = 0; e < 8; ++e) {
        float cv = bf2f(c0.s[e]), pv = bf2f(p0.s[e]);
        float c01 = bf2f(c1.s[e]); if (c01 > cv) { cv = c01; pv = bf2f(p1.s[e]); }
        float c10 = bf2f(c2.s[e]); if (c10 > cv) { cv = c10; pv = bf2f(p2.s[e]); }
        float c11 = bf2f(c3.s[e]); if (c11 > cv) { cv = c11; pv = bf2f(p3.s[e]); }
        rp.s[e] = f2bf(pv * 0.25f);
        rc.s[e] = f2bf(cv * 0.25f);
    }
    long ob = ((long)pix2) * 32 + k8 * 8;
    *(uint4*)(out + (long)(b * 2 + 0) * HW2 * 32 + ob) = rp.v;
    *(uint4*)(out + (long)(b * 2 + 1) * HW2 * 32 + ob) = rc.v;
}

// ---------------------------------------------------------------------------
extern "C" void kernel_launch(void* const* d_in, const int* in_sizes, int n_in,
                              void* d_out, int out_size, void* d_ws, size_t ws_size,
                              hipStream_t stream) {
    const float* x  = (const float*)d_in[0];
    const float* w1 = (const float*)d_in[1];
    const float* b1 = (const float*)d_in[2];
    const float* w2 = (const float*)d_in[3];
    const float* b2 = (const float*)d_in[4];
    const float* w3 = (const float*)d_in[5];
    const float* b3 = (const float*)d_in[6];
    const float* w4 = (const float*)d_in[7];
    const float* b4 = (const float*)d_in[8];
    const float* w5 = (const float*)d_in[9];
    const float* b5 = (const float*)d_in[10];
    const float* w6 = (const float*)d_in[11];
    const float* b6 = (const float*)d_in[12];
    const float* w7 = (const float*)d_in[13];
    const float* b7 = (const float*)d_in[14];

    const size_t HW1 = 512 * 512, HW2s = 256 * 256, HW3s = 128 * 128, HW4s = 64 * 64;

    // ---- weight arena (400000 B) ----
    const size_t WARENA = 400000;
    float* fa = (float*)d_ws;
    float *wt1 = fa;                 // 800 f
    float *s1 = wt1 + 800, *s2 = s1 + 32, *s3 = s2 + 32;   // reciprocal sums
    float *s4 = s3 + 32, *s5 = s4 + 32, *s6 = s5 + 32;     // ends at 992 f
    unsigned short* ua = (unsigned short*)((char*)d_ws + 4096);
    unsigned short *wf2 = ua;              // 25600
    unsigned short *wf3 = wf2 + 25600;     // 25600
    unsigned short *wf4 = wf3 + 25600;     // 18432
    unsigned short *wf5 = wf4 + 18432;     // 18432
    unsigned short *wf6 = wf5 + 18432;     // 18432 -> 213 KB < 400000-4096
    unsigned short* buf = (unsigned short*)((char*)d_ws + WARENA);

    // ---- stage buffers: channel-last bf16 [b*2+pc][HW][32] ----
    const size_t E1 = 2 * 2 * HW1 * 32;    // 33.55M ushort = 67.1 MB
    const size_t E2 = 2 * 2 * HW2s * 32, E3 = 2 * 2 * HW3s * 32, E4 = 2 * 2 * HW4s * 32;
    unsigned short* A = buf;
    unsigned short* B = A + E1;
    // lower-res alias inside B (sum = 22M ushorts <= E1)
    unsigned short* P = B;
    unsigned short* Q = P + E2;
    unsigned short* S = Q + E2;
    unsigned short* T = S + E3;
    unsigned short* U = T + E3;
    unsigned short* V = U + E4;

    if (ws_size < WARENA + 2 * E1 * sizeof(unsigned short)) return;  // 134.62 MB

    // ---- weight prep: single launch (107488 work items) ----
    wprep_k<<<420, 256, 0, stream>>>(w1, w2, w3, w4, w5, w6,
                                     wt1, s1, s2, s3, s4, s5, s6,
                                     wf2, wf3, wf4, wf5, wf6);

    dim3 blk(256);
    dim3 g1(16, 64, 2), g2(8, 32, 2), g3(4, 16, 2), g4(2, 8, 2);

    // ---- encoder ----
    conv1_k<<<g1, blk, 0, stream>>>(x, wt1, b1, s1, A, 512, 512);
    mconv_k<5, 1, false><<<g1, blk, 0, stream>>>(A, nullptr, wf2, b2, s2, B, nullptr, nullptr, nullptr, 512, 512);
    mconv_k<5, 1, false><<<g1, blk, 0, stream>>>(B, nullptr, wf3, b3, s3, A, nullptr, nullptr, nullptr, 512, 512);  // x1 in A

    pool_k<<<(int)((2 * HW2s * 4 + 255) / 256), blk, 0, stream>>>(A, P, 256, 256, (int)(2 * HW2s * 4));
    mconv_k<5, 1, false><<<g2, blk, 0, stream>>>(P, nullptr, wf2, b2, s2, Q, nullptr, nullptr, nullptr, 256, 256);
    mconv_k<5, 1, false><<<g2, blk, 0, stream>>>(Q, nullptr, wf3, b3, s3, P, nullptr, nullptr, nullptr, 256, 256);  // x2 in P

    pool_k<<<(int)((2 * HW3s * 4 + 255) / 256), blk, 0, stream>>>(P, S, 128, 128, (int)(2 * HW3s * 4));
    mconv_k<5, 1, false><<<g3, blk, 0, stream>>>(S, nullptr, wf2, b2, s2, T, nullptr, nullptr, nullptr, 128, 128);  // x3 in T

    pool_k<<<(int)((2 * HW4s * 4 + 255) / 256), blk, 0, stream>>>(T, U, 64, 64, (int)(2 * HW4s * 4));
    mconv_k<5, 1, false><<<g4, blk, 0, stream>>>(U, nullptr, wf2, b2, s2, V, nullptr, nullptr, nullptr, 64, 64);    // x4 in V

    // ---- decoder ----
    mconv_k<3, 2, false><<<g3, blk, 0, stream>>>(T, V, wf4, b4, s4, S, nullptr, nullptr, nullptr, 128, 128);        // x34 in S
    mconv_k<3, 2, false><<<g2, blk, 0, stream>>>(P, S, wf5, b5, s5, Q, nullptr, nullptr, nullptr, 256, 256);        // x23 in Q
    mconv_k<3, 2, true><<<g1, blk, 0, stream>>>(A, Q, wf6, b6, s6, nullptr, (float*)d_out, w7, b7, 512, 512);
}